// Round 4
// baseline (123.741 us; speedup 1.0000x reference)
//
#include <hip/hip_runtime.h>

#define NN 6144
#define DD 768
#define NB 48               // 6144 / 128 tile blocks per dim
#define NTILES 1176         // NB*(NB+1)/2 upper-triangular tiles
#define INV_T 14.285714285714286f
#define CMAX  14.285714285714286f

typedef int i32x4 __attribute__((ext_vector_type(4)));
typedef int i32x8 __attribute__((ext_vector_type(8)));
typedef float f32x4_t __attribute__((ext_vector_type(4)));

__device__ __forceinline__ void load_lds16(const void* g, void* l) {
    __builtin_amdgcn_global_load_lds((__attribute__((address_space(1))) void*)g,
                                     (__attribute__((address_space(3))) void*)l,
                                     16, 0, 0);
}

// Kernel 1: L2-normalize rows -> fp8 e4m3 (unit MX scale); zero den/num sums.
// One wave per row; 1536 blocks x 256 threads.
__global__ void norm_kernel(const float* __restrict__ feats,
                            unsigned int* __restrict__ fb8,   // 6144*192 uints
                            float* __restrict__ den_num) {    // [0..NN)=den, [NN..2NN)=num
    const int wid = threadIdx.x >> 6;
    const int lane = threadIdx.x & 63;
    const int row = blockIdx.x * 4 + wid;

    if (threadIdx.x < 8) den_num[blockIdx.x * 8 + threadIdx.x] = 0.0f;

    const float4* src = (const float4*)(feats + (size_t)row * DD);
    float4 v[3];
    float ss = 0.0f;
#pragma unroll
    for (int i = 0; i < 3; ++i) {
        v[i] = src[lane + i * 64];
        ss += v[i].x * v[i].x + v[i].y * v[i].y + v[i].z * v[i].z + v[i].w * v[i].w;
    }
#pragma unroll
    for (int m = 32; m >= 1; m >>= 1) ss += __shfl_xor(ss, m);
    const float sc = 1.0f / fmaxf(sqrtf(ss), 1e-12f);

#pragma unroll
    for (int i = 0; i < 3; ++i) {
        unsigned int w = 0;
        w = __builtin_amdgcn_cvt_pk_fp8_f32(v[i].x * sc, v[i].y * sc, w, 0);
        w = __builtin_amdgcn_cvt_pk_fp8_f32(v[i].z * sc, v[i].w * sc, w, 1);
        fb8[(size_t)row * 192 + lane + i * 64] = w;
    }
}

// Kernel 2: upper-triangular MX-fp8 MFMA Gram tiles + fused exp row/col sums.
//
// r8 (kept): ROLLED double-buffer ping-pong, statically named buffers,
// 2-trip `#pragma unroll 1` loop + peeled tail. No spill (VGPR 128).
//
// r9 (new): SUPERTILE-CHUNKED XCD REMAP (T1, 2-D). Evidence: r1's gemm
// showed FETCH 19.3 MB = 4x fb8 while LDS staging moves 230 MB/launch ->
// L2s thrash (each XCD asked to cache ~all 4.7 MB of fb8 in 4 MB) and most
// staging is served at Infinity-Cache latency/BW. Remap: partition the
// 48x48 panel triangle into 10 supertiles of 12x12 panels (4 diag x78 +
// 6 offdiag x144 = 1176 = 8*147), linearize in supertile order, and give
// each XCD (blockIdx%8, HW round-robin) one contiguous 147-tile chunk.
// Chunk footprint 1.2-3.5 MB -> fits the XCD's 4 MB L2, so staging
// re-reads come from the LOCAL L2, not L3. Also exact 147/XCD balance.
// Pure index remap: zero correctness risk.
__global__ __launch_bounds__(256, 2) void gemm_expsum_kernel(
        const unsigned char* __restrict__ fb8,
        float* __restrict__ den_sum, float* __restrict__ num_sum) {
    __shared__ __align__(16) char sA0[128 * 128];
    __shared__ __align__(16) char sA1[128 * 128];
    __shared__ __align__(16) char sB0[128 * 128];
    __shared__ __align__(16) char sB1[128 * 128];

    // ---- supertile-chunked remap: blockIdx -> (bi, bj), bi <= bj ----
    // Supertile order (SI,SJ) over 4x4 panel-grid (12 panels each):
    // (0,0)78 (0,1)144 (0,2)144 (0,3)144 (1,1)78 (1,2)144 (1,3)144
    // (2,2)78 (2,3)144 (3,3)78.  Prefix offsets below.
    const int chunk = blockIdx.x & 7;   // dispatch round-robin -> XCD id
    const int pos   = blockIdx.x >> 3;  // 0..146 within this XCD's chunk
    const int li    = chunk * 147 + pos;  // position in supertile-ordered list

    const int st_i[10]   = {0, 0, 0, 0, 1, 1, 1, 2, 2, 3};
    const int st_j[10]   = {0, 1, 2, 3, 1, 2, 3, 2, 3, 3};
    const int st_off[10] = {0, 78, 222, 366, 510, 588, 732, 876, 954, 1098};
    int s = 0;
#pragma unroll
    for (int k = 1; k < 10; ++k) s += (li >= st_off[k]);
    const int local = li - st_off[s];
    int bi, bj;
    if (st_i[s] == st_j[s]) {
        // 12x12 upper triangle: row r holds (12-r) entries
        int r = 0, rem2 = local;
        while (rem2 >= 12 - r) { rem2 -= 12 - r; ++r; }
        bi = st_i[s] * 12 + r;
        bj = st_j[s] * 12 + r + rem2;
    } else {
        bi = st_i[s] * 12 + local / 12;
        bj = st_j[s] * 12 + local % 12;
    }

    const bool isdiag = (bi == bj);
    const bool neardiag = (bj - bi) <= 1;
    const int i0 = bi * 128;
    const int j0 = bj * 128;

    const int t = threadIdx.x;
    const int lane = t & 63;
    const int wid = t >> 6;
    const int wm = wid >> 1;  // wave row (0..1)
    const int wn = wid & 1;   // wave col (0..1)

    // staging: thread t -> row = t>>3 (+32/issue), 16B chunk (t&7)^(row&7)
    const int srow = t >> 3;
    const int scb = ((t & 7) ^ (srow & 7)) * 16;
    const unsigned char* gA = fb8 + (size_t)(i0 + srow) * DD + scb;
    const unsigned char* gB = fb8 + (size_t)(j0 + srow) * DD + scb;
    const int ldsoff = wid * 1024;  // wave-uniform base; HW adds lane*16

    f32x4_t acc[4][4];
    const f32x4_t zz = {0.0f, 0.0f, 0.0f, 0.0f};
#pragma unroll
    for (int mi = 0; mi < 4; ++mi)
#pragma unroll
        for (int ni = 0; ni < 4; ++ni) acc[mi][ni] = zz;

    const int q = lane >> 4;
    const int mrow = lane & 15;
    const int x7 = lane & 7;
    const int c0 = ((q << 1) ^ x7) << 4;        // chunk byte offset, k-half 0
    const int c1 = (((q << 1) | 1) ^ x7) << 4;  // k-half 1

#define STAGE(dstA, dstB, k0)                                                 \
    {                                                                         \
        _Pragma("unroll")                                                     \
        for (int i = 0; i < 4; ++i) {                                         \
            load_lds16(gA + (size_t)(i * 32) * DD + (k0), (dstA) + ldsoff + i * 4096); \
            load_lds16(gB + (size_t)(i * 32) * DD + (k0), (dstB) + ldsoff + i * 4096); \
        }                                                                     \
    }

#define COMPUTE(srcA, srcB)                                                   \
    {                                                                         \
        i32x8 af[4];                                                          \
        _Pragma("unroll")                                                     \
        for (int mi = 0; mi < 4; ++mi) {                                      \
            const char* p = (srcA) + (wm * 64 + mi * 16 + mrow) * 128;        \
            i32x4 lo = *(const i32x4*)(p + c0);                               \
            i32x4 hi = *(const i32x4*)(p + c1);                               \
            af[mi] = __builtin_shufflevector(lo, hi, 0, 1, 2, 3, 4, 5, 6, 7); \
        }                                                                     \
        _Pragma("unroll")                                                     \
        for (int ni = 0; ni < 4; ++ni) {                                      \
            const char* p = (srcB) + (wn * 64 + ni * 16 + mrow) * 128;        \
            i32x4 lo = *(const i32x4*)(p + c0);                               \
            i32x4 hi = *(const i32x4*)(p + c1);                               \
            i32x8 bf = __builtin_shufflevector(lo, hi, 0, 1, 2, 3, 4, 5, 6, 7); \
            _Pragma("unroll")                                                 \
            for (int mi = 0; mi < 4; ++mi)                                    \
                acc[mi][ni] = __builtin_amdgcn_mfma_scale_f32_16x16x128_f8f6f4( \
                    af[mi], bf, acc[mi][ni], 0, 0,                            \
                    0, 0x7F7F7F7F, 0, 0x7F7F7F7F);                            \
        }                                                                     \
    }

    // Prologue: stage K-step 0; barrier drains vmcnt(0).
    STAGE(sA0, sB0, 0);
    __syncthreads();

    // Steady state: rolled ping-pong, one barrier per K-step.
#pragma unroll 1
    for (int kb = 0; kb < 2; ++kb) {
        const int k0 = kb * 256;
        STAGE(sA1, sB1, k0 + 128);
        COMPUTE(sA0, sB0);           // k = k0
        __syncthreads();
        STAGE(sA0, sB0, k0 + 256);
        COMPUTE(sA1, sB1);           // k = k0 + 128
        __syncthreads();
    }
    // Peeled tail: stage last step, compute k=512 then k=640.
    STAGE(sA1, sB1, 640);
    COMPUTE(sA0, sB0);               // k = 512
    __syncthreads();
    COMPUTE(sA1, sB1);               // k = 640

#undef STAGE
#undef COMPUTE

    // Epilogue. C/D layout: col=lane&15 (+ni*16), row=(lane>>4)*4+reg (+mi*16).
    const int colb = j0 + wn * 64 + mrow;
    const int rowb = i0 + wm * 64 + (q << 2);
    float cs[4] = {0.f, 0.f, 0.f, 0.f};
    float csn[4] = {0.f, 0.f, 0.f, 0.f};
#pragma unroll
    for (int mi = 0; mi < 4; ++mi) {
        float rsv[4] = {0.f, 0.f, 0.f, 0.f};
        float rsn[4] = {0.f, 0.f, 0.f, 0.f};
#pragma unroll
        for (int ni = 0; ni < 4; ++ni) {
            const int col = colb + ni * 16;
#pragma unroll
            for (int r = 0; r < 4; ++r) {
                const int row = rowb + mi * 16 + r;
                float e = __expf(__builtin_fmaf(acc[mi][ni][r], INV_T, -CMAX));
                if (isdiag && row == col) e = 0.0f;
                rsv[r] += e;
                cs[ni] += e;
                if (neardiag && (row / 3 == col / 3) && row != col) {
                    rsn[r] += e;
                    csn[ni] += e;
                }
            }
        }
#pragma unroll
        for (int r = 0; r < 4; ++r) {
            float v = rsv[r];
            v += __shfl_xor(v, 8);
            v += __shfl_xor(v, 4);
            v += __shfl_xor(v, 2);
            v += __shfl_xor(v, 1);
            if (mrow == 0) atomicAdd(&den_sum[rowb + mi * 16 + r], v);
        }
        if (neardiag) {
#pragma unroll
            for (int r = 0; r < 4; ++r) {
                float v = rsn[r];
                v += __shfl_xor(v, 8);
                v += __shfl_xor(v, 4);
                v += __shfl_xor(v, 2);
                v += __shfl_xor(v, 1);
                if (mrow == 0) atomicAdd(&num_sum[rowb + mi * 16 + r], v);
            }
        }
    }
    if (!isdiag) {
#pragma unroll
        for (int ni = 0; ni < 4; ++ni) {
            float v = cs[ni];
            v += __shfl_xor(v, 16);
            v += __shfl_xor(v, 32);
            if (q == 0) atomicAdd(&den_sum[colb + ni * 16], v);
        }
        if (neardiag) {
#pragma unroll
            for (int ni = 0; ni < 4; ++ni) {
                float v = csn[ni];
                v += __shfl_xor(v, 16);
                v += __shfl_xor(v, 32);
                if (q == 0) atomicAdd(&num_sum[colb + ni * 16], v);
            }
        }
    }
}

// Kernel 3: loss = mean(log(den) - log(num))  (CMAX cancels). Single block.
__global__ void finalize_kernel(const float* __restrict__ den_sum,
                                const float* __restrict__ num_sum,
                                float* __restrict__ out) {
    float local = 0.0f;
    for (int i = threadIdx.x; i < NN; i += 256) {
        local += logf(den_sum[i]) - logf(num_sum[i]);
    }
#pragma unroll
    for (int m = 32; m >= 1; m >>= 1) local += __shfl_xor(local, m);
    __shared__ float ws[4];
    if ((threadIdx.x & 63) == 0) ws[threadIdx.x >> 6] = local;
    __syncthreads();
    if (threadIdx.x == 0) out[0] = (ws[0] + ws[1] + ws[2] + ws[3]) / (float)NN;
}

extern "C" void kernel_launch(void* const* d_in, const int* in_sizes, int n_in,
                              void* d_out, int out_size, void* d_ws, size_t ws_size,
                              hipStream_t stream) {
    const float* feats = (const float*)d_in[0];
    float* out = (float*)d_out;

    char* ws = (char*)d_ws;
    unsigned int* fb8 = (unsigned int*)ws;                 // 6144*768 = 4718592 B
    float* den_num    = (float*)(ws + 4718592);            // 2*6144*4 B
    float* den_sum    = den_num;
    float* num_sum    = den_num + NN;

    norm_kernel<<<NN / 4, 256, 0, stream>>>(feats, fb8, den_num);
    gemm_expsum_kernel<<<NTILES, 256, 0, stream>>>((const unsigned char*)fb8,
                                                   den_sum, num_sum);
    finalize_kernel<<<1, 256, 0, stream>>>(den_sum, num_sum, out);
}

// Round 5
// 114.887 us; speedup vs baseline: 1.0771x; 1.0771x over previous
//
#include <hip/hip_runtime.h>

#define NN 6144
#define DD 768
#define NB 48               // 6144 / 128 tile blocks per dim
#define NTILES 1176         // NB*(NB+1)/2 upper-triangular tiles
#define INV_T 14.285714285714286f
#define CMAX  14.285714285714286f

typedef int i32x4 __attribute__((ext_vector_type(4)));
typedef int i32x8 __attribute__((ext_vector_type(8)));
typedef float f32x4_t __attribute__((ext_vector_type(4)));

__device__ __forceinline__ void load_lds16(const void* g, void* l) {
    __builtin_amdgcn_global_load_lds((__attribute__((address_space(1))) void*)g,
                                     (__attribute__((address_space(3))) void*)l,
                                     16, 0, 0);
}

// Kernel 1: L2-normalize rows -> fp8 e4m3 (unit MX scale); zero den/num sums.
// One wave per row; 1536 blocks x 256 threads.
__global__ void norm_kernel(const float* __restrict__ feats,
                            unsigned int* __restrict__ fb8,   // 6144*192 uints
                            float* __restrict__ den_num) {    // [0..NN)=den, [NN..2NN)=num
    const int wid = threadIdx.x >> 6;
    const int lane = threadIdx.x & 63;
    const int row = blockIdx.x * 4 + wid;

    if (threadIdx.x < 8) den_num[blockIdx.x * 8 + threadIdx.x] = 0.0f;

    const float4* src = (const float4*)(feats + (size_t)row * DD);
    float4 v[3];
    float ss = 0.0f;
#pragma unroll
    for (int i = 0; i < 3; ++i) {
        v[i] = src[lane + i * 64];
        ss += v[i].x * v[i].x + v[i].y * v[i].y + v[i].z * v[i].z + v[i].w * v[i].w;
    }
#pragma unroll
    for (int m = 32; m >= 1; m >>= 1) ss += __shfl_xor(ss, m);
    const float sc = 1.0f / fmaxf(sqrtf(ss), 1e-12f);

#pragma unroll
    for (int i = 0; i < 3; ++i) {
        unsigned int w = 0;
        w = __builtin_amdgcn_cvt_pk_fp8_f32(v[i].x * sc, v[i].y * sc, w, 0);
        w = __builtin_amdgcn_cvt_pk_fp8_f32(v[i].z * sc, v[i].w * sc, w, 1);
        fb8[(size_t)row * 192 + lane + i * 64] = w;
    }
}

// Kernel 2: upper-triangular MX-fp8 MFMA Gram tiles + fused exp row/col sums.
//
// r10: COUNTED-VMCNT PIPELINE (T4) + setprio (T5).
//  Evidence trail: r6 single-buffer 56.6us; r8 "dbuf" w/ __syncthreads 55us
//  (identical) -- because __syncthreads forces s_waitcnt vmcnt(0), draining
//  the prefetch issued AT THE TOP OF THE SAME STEP. Lockstep waves all stall
//  at the same barrier -> MfmaUtil*dur = 5.4us of work in a 55us kernel.
//  Fix per guide m218 (counted-vs-drain0 = +38..73%): each STAGE is exactly
//  8 global_load_lds per wave and they are the ONLY vmcnt ops in the K-loop,
//  so `s_waitcnt vmcnt(8)` waits the 8 OLDEST (current tile) and leaves the
//  prefetch in flight across a RAW s_barrier. Trailing barrier is raw +
//  compiler memory fence (NOT __syncthreads - that re-drains). ds_reads are
//  retired before barrier arrival (compiler lgkmcnt before last MFMA use),
//  so raw barriers are race-free; no ds_writes exist (gload_lds is vmcnt).
//  Supertile decode rewritten ARRAY-FREE (pure arithmetic): a spilled const
//  array would emit scratch buffer ops that count in vmcnt and break the
//  vmcnt(8) discipline.
//  setprio(1) around the MFMA cluster: legitimate now that counted-vmcnt
//  creates a stage/compute wave role split (m218b: +21-25% on top).
//
// r9 (kept): supertile-chunked XCD remap - FETCH 19.3->10.9 MB confirmed
// L2-locality mechanism (time-neutral alone, keeps staging at L2 latency
// so the one-step prefetch distance fully covers it).
// r8 (kept): rolled ping-pong, statically named buffers (LLVM proves
// sA0/sA1 distinct LDS objects -> no conservative waits between the
// prefetch and the ds_reads), no spill.
__global__ __launch_bounds__(256, 2) void gemm_expsum_kernel(
        const unsigned char* __restrict__ fb8,
        float* __restrict__ den_sum, float* __restrict__ num_sum) {
    __shared__ __align__(16) char sA0[128 * 128];
    __shared__ __align__(16) char sA1[128 * 128];
    __shared__ __align__(16) char sB0[128 * 128];
    __shared__ __align__(16) char sB1[128 * 128];

    // ---- supertile-chunked remap: blockIdx -> (bi, bj), bi <= bj ----
    // 4x4 supertile grid of 12x12 panels; row-order supertiles; each XCD
    // (blockIdx&7, HW round-robin) gets one contiguous 147-tile chunk
    // (1176 = 8*147 exact). Footprint/chunk 1.7-3.4 MB -> fits 4MB L2.
    // ALL-ARITHMETIC decode (no arrays -> nothing can spill to scratch).
    {
    }
    const int chunk = blockIdx.x & 7;
    const int pos   = blockIdx.x >> 3;
    int rem = chunk * 147 + pos;  // position in supertile-ordered list

    int si = 0;
    while (rem >= 510 - 144 * si) { rem -= 510 - 144 * si; ++si; }  // rowsz=78+(3-si)*144
    int bi, bj;
    if (rem < 78) {               // diagonal supertile (si,si): 12x12 triangle
        int r = 0;
        while (rem >= 12 - r) { rem -= 12 - r; ++r; }
        bi = si * 12 + r;
        bj = si * 12 + r + rem;
    } else {                      // off-diagonal supertiles, 144 tiles each
        rem -= 78;
        const int sj = si + 1 + rem / 144;
        const int lo = rem % 144;
        bi = si * 12 + lo / 12;
        bj = sj * 12 + lo % 12;
    }

    const bool isdiag = (bi == bj);
    const bool neardiag = (bj - bi) <= 1;
    const int i0 = bi * 128;
    const int j0 = bj * 128;

    const int t = threadIdx.x;
    const int lane = t & 63;
    const int wid = t >> 6;
    const int wm = wid >> 1;  // wave row (0..1)
    const int wn = wid & 1;   // wave col (0..1)

    // staging: thread t -> row = t>>3 (+32/issue), 16B chunk (t&7)^(row&7)
    const int srow = t >> 3;
    const int scb = ((t & 7) ^ (srow & 7)) * 16;
    const unsigned char* gA = fb8 + (size_t)(i0 + srow) * DD + scb;
    const unsigned char* gB = fb8 + (size_t)(j0 + srow) * DD + scb;
    const int ldsoff = wid * 1024;  // wave-uniform base; HW adds lane*16

    f32x4_t acc[4][4];
    const f32x4_t zz = {0.0f, 0.0f, 0.0f, 0.0f};
#pragma unroll
    for (int mi = 0; mi < 4; ++mi)
#pragma unroll
        for (int ni = 0; ni < 4; ++ni) acc[mi][ni] = zz;

    const int q = lane >> 4;
    const int mrow = lane & 15;
    const int x7 = lane & 7;
    const int c0 = ((q << 1) ^ x7) << 4;        // chunk byte offset, k-half 0
    const int c1 = (((q << 1) | 1) ^ x7) << 4;  // k-half 1

// 8 global_load_lds per wave per STAGE — the ONLY vmcnt ops in the K-loop.
#define STAGE(dstA, dstB, k0)                                                 \
    {                                                                         \
        _Pragma("unroll")                                                     \
        for (int i = 0; i < 4; ++i) {                                         \
            load_lds16(gA + (size_t)(i * 32) * DD + (k0), (dstA) + ldsoff + i * 4096); \
            load_lds16(gB + (size_t)(i * 32) * DD + (k0), (dstB) + ldsoff + i * 4096); \
        }                                                                     \
    }

#define COMPUTE(srcA, srcB)                                                   \
    {                                                                         \
        __builtin_amdgcn_s_setprio(1);                                        \
        i32x8 af[4];                                                          \
        _Pragma("unroll")                                                     \
        for (int mi = 0; mi < 4; ++mi) {                                      \
            const char* p = (srcA) + (wm * 64 + mi * 16 + mrow) * 128;        \
            i32x4 lo = *(const i32x4*)(p + c0);                               \
            i32x4 hi = *(const i32x4*)(p + c1);                               \
            af[mi] = __builtin_shufflevector(lo, hi, 0, 1, 2, 3, 4, 5, 6, 7); \
        }                                                                     \
        _Pragma("unroll")                                                     \
        for (int ni = 0; ni < 4; ++ni) {                                      \
            const char* p = (srcB) + (wn * 64 + ni * 16 + mrow) * 128;        \
            i32x4 lo = *(const i32x4*)(p + c0);                               \
            i32x4 hi = *(const i32x4*)(p + c1);                               \
            i32x8 bf = __builtin_shufflevector(lo, hi, 0, 1, 2, 3, 4, 5, 6, 7); \
            _Pragma("unroll")                                                 \
            for (int mi = 0; mi < 4; ++mi)                                    \
                acc[mi][ni] = __builtin_amdgcn_mfma_scale_f32_16x16x128_f8f6f4( \
                    af[mi], bf, acc[mi][ni], 0, 0,                            \
                    0, 0x7F7F7F7F, 0, 0x7F7F7F7F);                            \
        }                                                                     \
        __builtin_amdgcn_s_setprio(0);                                        \
    }

// Wait for the 8 OLDEST loads (current tile) only; prefetch stays in flight.
#define WAITBAR_KEEP8                                                         \
    asm volatile("s_waitcnt vmcnt(8)" ::: "memory");                          \
    __builtin_amdgcn_s_barrier();

#define WAITBAR_DRAIN                                                         \
    asm volatile("s_waitcnt vmcnt(0)" ::: "memory");                          \
    __builtin_amdgcn_s_barrier();

// Buffer-reuse barrier: compiler-level memory fence pins ds_reads above it;
// raw s_barrier (NO vmcnt drain — that's the r8 disease).
#define ENDBAR                                                                \
    asm volatile("" ::: "memory");                                            \
    __builtin_amdgcn_s_barrier();

    // Prologue: stage tile 0 (8 in flight).
    STAGE(sA0, sB0, 0);

    // Steady state: 2 tiles in flight, wait-oldest-8, one raw barrier pair
    // per K-step. Computes hit k=0,128,256,384; tail does 512,640.
#pragma unroll 1
    for (int kb = 0; kb < 2; ++kb) {
        const int k0 = kb * 256;
        STAGE(sA1, sB1, k0 + 128);   // 16 in flight
        WAITBAR_KEEP8                // tile(k0) landed; prefetch in flight
        COMPUTE(sA0, sB0);           // k = k0
        ENDBAR                       // sA0/sB0 safe to overwrite
        STAGE(sA0, sB0, k0 + 256);   // 16 in flight
        WAITBAR_KEEP8
        COMPUTE(sA1, sB1);           // k = k0 + 128
        ENDBAR
    }
    // Tail: k=512 then k=640.
    STAGE(sA1, sB1, 640);            // 16 in flight
    WAITBAR_KEEP8
    COMPUTE(sA0, sB0);               // k = 512
    WAITBAR_DRAIN                    // drain tile(640); also reuse-barrier
    COMPUTE(sA1, sB1);               // k = 640

#undef STAGE
#undef COMPUTE
#undef WAITBAR_KEEP8
#undef WAITBAR_DRAIN
#undef ENDBAR

    // Epilogue. C/D layout: col=lane&15 (+ni*16), row=(lane>>4)*4+reg (+mi*16).
    const int colb = j0 + wn * 64 + mrow;
    const int rowb = i0 + wm * 64 + (q << 2);
    float cs[4] = {0.f, 0.f, 0.f, 0.f};
    float csn[4] = {0.f, 0.f, 0.f, 0.f};
#pragma unroll
    for (int mi = 0; mi < 4; ++mi) {
        float rsv[4] = {0.f, 0.f, 0.f, 0.f};
        float rsn[4] = {0.f, 0.f, 0.f, 0.f};
#pragma unroll
        for (int ni = 0; ni < 4; ++ni) {
            const int col = colb + ni * 16;
#pragma unroll
            for (int r = 0; r < 4; ++r) {
                const int row = rowb + mi * 16 + r;
                float e = __expf(__builtin_fmaf(acc[mi][ni][r], INV_T, -CMAX));
                if (isdiag && row == col) e = 0.0f;
                rsv[r] += e;
                cs[ni] += e;
                if (neardiag && (row / 3 == col / 3) && row != col) {
                    rsn[r] += e;
                    csn[ni] += e;
                }
            }
        }
#pragma unroll
        for (int r = 0; r < 4; ++r) {
            float v = rsv[r];
            v += __shfl_xor(v, 8);
            v += __shfl_xor(v, 4);
            v += __shfl_xor(v, 2);
            v += __shfl_xor(v, 1);
            if (mrow == 0) atomicAdd(&den_sum[rowb + mi * 16 + r], v);
        }
        if (neardiag) {
#pragma unroll
            for (int r = 0; r < 4; ++r) {
                float v = rsn[r];
                v += __shfl_xor(v, 8);
                v += __shfl_xor(v, 4);
                v += __shfl_xor(v, 2);
                v += __shfl_xor(v, 1);
                if (mrow == 0) atomicAdd(&num_sum[rowb + mi * 16 + r], v);
            }
        }
    }
    if (!isdiag) {
#pragma unroll
        for (int ni = 0; ni < 4; ++ni) {
            float v = cs[ni];
            v += __shfl_xor(v, 16);
            v += __shfl_xor(v, 32);
            if (q == 0) atomicAdd(&den_sum[colb + ni * 16], v);
        }
        if (neardiag) {
#pragma unroll
            for (int ni = 0; ni < 4; ++ni) {
                float v = csn[ni];
                v += __shfl_xor(v, 16);
                v += __shfl_xor(v, 32);
                if (q == 0) atomicAdd(&num_sum[colb + ni * 16], v);
            }
        }
    }
}

// Kernel 3: loss = mean(log(den) - log(num))  (CMAX cancels). Single block.
__global__ void finalize_kernel(const float* __restrict__ den_sum,
                                const float* __restrict__ num_sum,
                                float* __restrict__ out) {
    float local = 0.0f;
    for (int i = threadIdx.x; i < NN; i += 256) {
        local += logf(den_sum[i]) - logf(num_sum[i]);
    }
#pragma unroll
    for (int m = 32; m >= 1; m >>= 1) local += __shfl_xor(local, m);
    __shared__ float ws[4];
    if ((threadIdx.x & 63) == 0) ws[threadIdx.x >> 6] = local;
    __syncthreads();
    if (threadIdx.x == 0) out[0] = (ws[0] + ws[1] + ws[2] + ws[3]) / (float)NN;
}

extern "C" void kernel_launch(void* const* d_in, const int* in_sizes, int n_in,
                              void* d_out, int out_size, void* d_ws, size_t ws_size,
                              hipStream_t stream) {
    const float* feats = (const float*)d_in[0];
    float* out = (float*)d_out;

    char* ws = (char*)d_ws;
    unsigned int* fb8 = (unsigned int*)ws;                 // 6144*768 = 4718592 B
    float* den_num    = (float*)(ws + 4718592);            // 2*6144*4 B
    float* den_sum    = den_num;
    float* num_sum    = den_num + NN;

    norm_kernel<<<NN / 4, 256, 0, stream>>>(feats, fb8, den_num);
    gemm_expsum_kernel<<<NTILES, 256, 0, stream>>>((const unsigned char*)fb8,
                                                   den_sum, num_sum);
    finalize_kernel<<<1, 256, 0, stream>>>(den_sum, num_sum, out);
}